// Round 3
// baseline (429.457 us; speedup 1.0000x reference)
//
#include <hip/hip_runtime.h>
#include <hip/hip_cooperative_groups.h>
#include <math.h>

namespace cg = cooperative_groups;

// CBTree contraction, B=4, L=9, d=256.
// g-combine before GEMM (linearity):
//   gL[p]=sum_b lc[b]*h[4p+b], gR[p]=sum_b rc[b]*h[4p+b]
//   h_new[p] = tanh([gL|gR] @ [Wl|Wr].T + vec[p])  (M=n_par, K=512, N=256)
// Round 7: single cooperative kernel. Round 6 showed the MFMA levels are not
// the cost (3x A-read cut -> zero total change); the ~95us unexplained gap is
// the 10-kernel dependent launch chain. Fuse all levels into ONE cooperative
// launch with grid.sync() between levels (9 launch gaps -> 8 grid syncs).
// Numeric path identical to round 6 (absmax 0.0117): split-A hi/lo MFMA,
// fp32 intermediates for L6..L1, fp32 tail levels.

typedef __bf16 bf16x8 __attribute__((ext_vector_type(8)));
typedef __bf16 bf16x4 __attribute__((ext_vector_type(4)));
typedef float f32x4 __attribute__((ext_vector_type(4)));

__device__ __forceinline__ float fast_tanh(float x) {
    float ax = fabsf(x);
    float t = __builtin_amdgcn_exp2f(ax * -2.885390082f);  // 2*log2(e)
    float r = (1.0f - t) * __builtin_amdgcn_rcpf(1.0f + t);
    return copysignf(r, x);
}

// ---------------------------------------------------------------------------
// W swizzle phase: Wfrag holds [Wl|Wr] (N=256 x K=512) in MFMA B-frag order.
// Fragment (J,T): 64 lanes x 8 bf16; lane L holds B[k=T*32+(L>>4)*8+j][n=J*16+(L&15)]
//   = Wcat[n][k].  Flat: Wfrag[(((J*16)+T)*64 + L)*8 + j]
// ---------------------------------------------------------------------------
__device__ __forceinline__ void wconv_body(
    const float* __restrict__ Wl, const float* __restrict__ Wr,
    __bf16* __restrict__ Wfrag)
{
    for (int t = blockIdx.x * 256 + (int)threadIdx.x; t < 16384;
         t += gridDim.x * 256) {
        const int L = t & 63;
        const int TJ = t >> 6;
        const int T = TJ & 15;
        const int J = TJ >> 4;
        const int n = J * 16 + (L & 15);
        const int k = T * 32 + (L >> 4) * 8;
        const float* src = (k < 256) ? (Wl + (size_t)n * 256 + k)
                                     : (Wr + (size_t)n * 256 + (k - 256));
        const float4 f0 = *reinterpret_cast<const float4*>(src);
        const float4 f1 = *reinterpret_cast<const float4*>(src + 4);
        bf16x8 o;
        o[0] = (__bf16)f0.x; o[1] = (__bf16)f0.y; o[2] = (__bf16)f0.z; o[3] = (__bf16)f0.w;
        o[4] = (__bf16)f1.x; o[5] = (__bf16)f1.y; o[6] = (__bf16)f1.z; o[7] = (__bf16)f1.w;
        *reinterpret_cast<bf16x8*>(Wfrag + (size_t)t * 8) = o;
    }
}

// ---------------------------------------------------------------------------
// MFMA GEMM level body, single-pass child reads + split-A (hi+lo bf16).
// Tile 32 x 256 (full N), 256 threads (4 waves, 2x2). Per T-iter (T=0..7):
// read children cols [T*32,T*32+32) ONCE, build {gL_hi,gL_lo,gR_hi,gR_lo}
// in LDS, run K-steps T (gL x B-set T) and T+8 (gR x B-set T+8), each as
// hi-MFMA + lo-MFMA reusing the same B fragments.
// ---------------------------------------------------------------------------
template <typename CT, typename OT>
__device__ __forceinline__ void mfma_body(
    const CT* __restrict__ h,          // (4*M, 256) children
    const __bf16* __restrict__ Wfrag,  // swizzled weights
    const float* __restrict__ vec,     // (M, 256)
    OT* __restrict__ out,              // (M, 256)
    int mBase, __bf16* Alds)
{
    const int tid = threadIdx.x;
    const int lane = tid & 63;
    const int w = tid >> 6;
    const int wr = w >> 1, wc = w & 1;        // wave tile: rows wr*16, cols wc*128

    f32x4 acc[8] = {};

    // A staging: 8 threads per parent row, 4 cols each
    const int sm  = tid >> 3;                 // parent row 0..31
    const int skq = (tid & 7) * 4;            // col offset 0..28
    const CT* hb = h + (size_t)(mBase + sm) * 1024 + skq;

    float c0[4], c1[4], c2[4], c3[4];
    auto load_h = [&](int k0) {
        if constexpr (sizeof(CT) == 4) {      // fp32 children
            const float4 a = *reinterpret_cast<const float4*>(hb + k0);
            const float4 b = *reinterpret_cast<const float4*>(hb + k0 + 256);
            const float4 c = *reinterpret_cast<const float4*>(hb + k0 + 512);
            const float4 d = *reinterpret_cast<const float4*>(hb + k0 + 768);
            c0[0] = a.x; c0[1] = a.y; c0[2] = a.z; c0[3] = a.w;
            c1[0] = b.x; c1[1] = b.y; c1[2] = b.z; c1[3] = b.w;
            c2[0] = c.x; c2[1] = c.y; c2[2] = c.z; c2[3] = c.w;
            c3[0] = d.x; c3[1] = d.y; c3[2] = d.z; c3[3] = d.w;
        } else {                              // bf16 children
            const bf16x4 a = *reinterpret_cast<const bf16x4*>(hb + k0);
            const bf16x4 b = *reinterpret_cast<const bf16x4*>(hb + k0 + 256);
            const bf16x4 c = *reinterpret_cast<const bf16x4*>(hb + k0 + 512);
            const bf16x4 d = *reinterpret_cast<const bf16x4*>(hb + k0 + 768);
#pragma unroll
            for (int j = 0; j < 4; ++j) {
                c0[j] = (float)a[j]; c1[j] = (float)b[j];
                c2[j] = (float)c[j]; c3[j] = (float)d[j];
            }
        }
    };

    auto store_A = [&]() {
        constexpr float C23 = 2.0f / 3.0f, C13 = 1.0f / 3.0f;
        bf16x4 glh, gll, grh, grl;
#pragma unroll
        for (int j = 0; j < 4; ++j) {
            const float gl = c0[j] + C23 * c1[j] + C13 * c2[j];
            const float gr = C13 * c1[j] + C23 * c2[j] + c3[j];
            glh[j] = (__bf16)gl;
            gll[j] = (__bf16)(gl - (float)glh[j]);
            grh[j] = (__bf16)gr;
            grl[j] = (__bf16)(gr - (float)grh[j]);
        }
        const int o = sm * 40 + skq;
        *reinterpret_cast<bf16x4*>(&Alds[o])        = glh;
        *reinterpret_cast<bf16x4*>(&Alds[o + 1280]) = gll;
        *reinterpret_cast<bf16x4*>(&Alds[o + 2560]) = grh;
        *reinterpret_cast<bf16x4*>(&Alds[o + 3840]) = grl;
    };

    // B fragments: buf0 = gL sets (K-steps 0..7), buf1 = gR sets (8..15),
    // each prefetched one full iteration ahead (L2-hot Wfrag).
    bf16x8 bfr[2][8];
    const __bf16* Wb = Wfrag + ((size_t)wc * 128 * 64 + lane) * 8;  // J0=wc*8
    auto load_B = [&](int s, int buf) {
        const __bf16* p = Wb + (size_t)s * 512;
#pragma unroll
        for (int j = 0; j < 8; ++j)
            bfr[buf][j] = *reinterpret_cast<const bf16x8*>(p + (size_t)j * 8192);
    };

    load_h(0);
    load_B(0, 0);
    load_B(8, 1);

    const int arow = (wr * 16 + (lane & 15)) * 40 + (lane >> 4) * 8;

    for (int T = 0; T < 8; ++T) {
        __syncthreads();              // all waves done with previous A tile
        store_A();
        __syncthreads();

        if (T < 7) load_h((T + 1) * 32);   // prefetch next child chunk

        const bf16x8 afLh = *reinterpret_cast<const bf16x8*>(&Alds[arow]);
        const bf16x8 afLl = *reinterpret_cast<const bf16x8*>(&Alds[arow + 1280]);
#pragma unroll
        for (int j = 0; j < 8; ++j)
            acc[j] = __builtin_amdgcn_mfma_f32_16x16x32_bf16(
                afLh, bfr[0][j], acc[j], 0, 0, 0);
#pragma unroll
        for (int j = 0; j < 8; ++j)
            acc[j] = __builtin_amdgcn_mfma_f32_16x16x32_bf16(
                afLl, bfr[0][j], acc[j], 0, 0, 0);

        if (T < 7) load_B(T + 1, 0);       // next gL B-set

        const bf16x8 afRh = *reinterpret_cast<const bf16x8*>(&Alds[arow + 2560]);
        const bf16x8 afRl = *reinterpret_cast<const bf16x8*>(&Alds[arow + 3840]);
#pragma unroll
        for (int j = 0; j < 8; ++j)
            acc[j] = __builtin_amdgcn_mfma_f32_16x16x32_bf16(
                afRh, bfr[1][j], acc[j], 0, 0, 0);
#pragma unroll
        for (int j = 0; j < 8; ++j)
            acc[j] = __builtin_amdgcn_mfma_f32_16x16x32_bf16(
                afRl, bfr[1][j], acc[j], 0, 0, 0);

        if (T < 7) load_B(T + 9, 1);       // next gR B-set
    }

    // epilogue: C/D layout col=lane&15, row=(lane>>4)*4+reg
    const int q = lane >> 4, n16 = lane & 15;
    const int mrow = mBase + wr * 16 + q * 4;
#pragma unroll
    for (int j = 0; j < 8; ++j) {
        const int n = wc * 128 + j * 16 + n16;
#pragma unroll
        for (int r = 0; r < 4; ++r) {
            const size_t idx = (size_t)(mrow + r) * 256 + n;
            out[idx] = (OT)fast_tanh(acc[j][r] + vec[idx]);
        }
    }
}

// ---------------------------------------------------------------------------
// Tiny-level body: one wave per output element, fully fp32 (exact),
// grid-stride over nout = M*256 outputs.
// ---------------------------------------------------------------------------
__device__ __forceinline__ void small_body(
    const float* __restrict__ h, const float* __restrict__ Wl,
    const float* __restrict__ Wr, const float* __restrict__ vec,
    float* __restrict__ out, int nout)
{
    const int gw = blockIdx.x * 4 + ((int)threadIdx.x >> 6);
    const int lane = threadIdx.x & 63;
    const int nw = gridDim.x * 4;

    for (int o = gw; o < nout; o += nw) {
        const int m = o >> 8;
        const int n = o & 255;

        const float* hbp = h + (size_t)m * 1024 + lane * 4;
        const float4 c0 = *reinterpret_cast<const float4*>(hbp);
        const float4 c1 = *reinterpret_cast<const float4*>(hbp + 256);
        const float4 c2 = *reinterpret_cast<const float4*>(hbp + 512);
        const float4 c3 = *reinterpret_cast<const float4*>(hbp + 768);
        const float4 wl = *reinterpret_cast<const float4*>(Wl + (size_t)n * 256 + lane * 4);
        const float4 wr = *reinterpret_cast<const float4*>(Wr + (size_t)n * 256 + lane * 4);

        constexpr float C23 = 2.0f / 3.0f;
        constexpr float C13 = 1.0f / 3.0f;
        const float f0[4] = {c0.x, c0.y, c0.z, c0.w};
        const float f1[4] = {c1.x, c1.y, c1.z, c1.w};
        const float f2[4] = {c2.x, c2.y, c2.z, c2.w};
        const float f3[4] = {c3.x, c3.y, c3.z, c3.w};
        const float wlv[4] = {wl.x, wl.y, wl.z, wl.w};
        const float wrv[4] = {wr.x, wr.y, wr.z, wr.w};
        float acc = 0.0f;
#pragma unroll
        for (int j = 0; j < 4; ++j) {
            const float gl = f0[j] + C23 * f1[j] + C13 * f2[j];
            const float gr = C13 * f1[j] + C23 * f2[j] + f3[j];
            acc += gl * wlv[j] + gr * wrv[j];
        }
#pragma unroll
        for (int off = 32; off >= 1; off >>= 1) acc += __shfl_xor(acc, off, 64);

        if (lane == 0)
            out[(size_t)m * 256 + n] = fast_tanh(acc + vec[(size_t)m * 256 + n]);
    }
}

// ---------------------------------------------------------------------------
// The whole tree in one cooperative launch. All phases grid-stride, so any
// grid size is correct; host caps grid at co-resident occupancy.
// node offsets (rows): off[l] = (4^l - 1)/3:
//   0,1,5,21,85,341,1365,5461,21845 ; leaves at 21845 (65536 rows)
// ---------------------------------------------------------------------------
__global__ __launch_bounds__(256, 2) void cbt_all(
    const float* __restrict__ vectors,
    const float* __restrict__ Wl, const float* __restrict__ Wr,
    float* __restrict__ outF,
    __bf16* __restrict__ buf7, float* __restrict__ buf6,
    float* __restrict__ buf5, float* __restrict__ buf4,
    float* __restrict__ buf3, float* __restrict__ buf2,
    float* __restrict__ buf1, __bf16* __restrict__ Wfrag)
{
    // rows of 32 bf16, stride 40 (80B) -> <=2-way bank aliasing on b128 reads
    // regions: gL_hi @0, gL_lo @1280, gR_hi @2560, gR_lo @3840 (elements)
    __shared__ __align__(16) __bf16 Alds[4 * 32 * 40];

    cg::grid_group grid = cg::this_grid();

    // phase W
    wconv_body(Wl, Wr, Wfrag);
    grid.sync();

    // L7: fp32 leaves -> bf16 out, M=16384 (512 tiles)
    for (int t = blockIdx.x; t < 512; t += gridDim.x)
        mfma_body<float, __bf16>(vectors + (size_t)21845 * 256, Wfrag,
                                 vectors + (size_t)5461 * 256, buf7, t * 32, Alds);
    grid.sync();

    // L6: bf16 -> fp32, M=4096 (128 tiles)
    for (int t = blockIdx.x; t < 128; t += gridDim.x)
        mfma_body<__bf16, float>(buf7, Wfrag,
                                 vectors + (size_t)1365 * 256, buf6, t * 32, Alds);
    grid.sync();

    // L5: fp32 -> fp32, M=1024 (32 tiles)
    for (int t = blockIdx.x; t < 32; t += gridDim.x)
        mfma_body<float, float>(buf6, Wfrag,
                                vectors + (size_t)341 * 256, buf5, t * 32, Alds);
    grid.sync();

    // L4: fp32 -> fp32, M=256 (8 tiles)
    for (int t = blockIdx.x; t < 8; t += gridDim.x)
        mfma_body<float, float>(buf5, Wfrag,
                                vectors + (size_t)85 * 256, buf4, t * 32, Alds);
    grid.sync();

    // L3..L0: wave-per-output, fully fp32
    small_body(buf4, Wl, Wr, vectors + (size_t)21 * 256, buf3, 64 * 256);
    grid.sync();
    small_body(buf3, Wl, Wr, vectors + (size_t)5 * 256, buf2, 16 * 256);
    grid.sync();
    small_body(buf2, Wl, Wr, vectors + (size_t)1 * 256, buf1, 4 * 256);
    grid.sync();
    small_body(buf1, Wl, Wr, vectors, outF, 1 * 256);
}

// ---------------------------------------------------------------------------
extern "C" void kernel_launch(void* const* d_in, const int* in_sizes, int n_in,
                              void* d_out, int out_size, void* d_ws, size_t ws_size,
                              hipStream_t stream) {
    const float* vectors = (const float*)d_in[0];
    const float* Wl = (const float*)d_in[1];
    const float* Wr = (const float*)d_in[2];
    float* outF = (float*)d_out;

    // ws layout:
    //   buf7  bf16  16384x256 (8 MB)   L7 out
    //   buf6  f32    4096x256 (4 MB)   L6 out
    //   buf5  f32    1024x256 (1 MB)   L5 out
    //   buf4  f32     256x256 (256 KB) L4 out
    //   buf3  f32      64x256 (64 KB)  L3 out
    //   buf2  f32      16x256 (16 KB)  L2 out
    //   buf1  f32       4x256 (4 KB)   L1 out
    //   Wfrag bf16  16384x8   (256 KB)
    char* p = (char*)d_ws;
    __bf16* buf7 = (__bf16*)p;           p += (size_t)16384 * 256 * 2;
    float*  buf6 = (float*)p;            p += (size_t)4096 * 256 * 4;
    float*  buf5 = (float*)p;            p += (size_t)1024 * 256 * 4;
    float*  buf4 = (float*)p;            p += (size_t)256 * 256 * 4;
    float*  buf3 = (float*)p;            p += (size_t)64 * 256 * 4;
    float*  buf2 = (float*)p;            p += (size_t)16 * 256 * 4;
    float*  buf1 = (float*)p;            p += (size_t)4 * 256 * 4;
    __bf16* Wfrag = (__bf16*)p;

    // cap grid at co-resident occupancy (cooperative-launch requirement);
    // 512 tiles is the max useful grid (L7). MI355X has 256 CUs.
    int nb = 0;
    if (hipOccupancyMaxActiveBlocksPerMultiprocessor(&nb, (const void*)cbt_all,
                                                     256, 0) != hipSuccess || nb < 1)
        nb = 1;
    int gridSz = nb * 256;
    if (gridSz > 512) gridSz = 512;

    void* args[] = {
        (void*)&vectors, (void*)&Wl, (void*)&Wr, (void*)&outF,
        (void*)&buf7, (void*)&buf6, (void*)&buf5, (void*)&buf4,
        (void*)&buf3, (void*)&buf2, (void*)&buf1, (void*)&Wfrag,
    };
    hipLaunchCooperativeKernel((const void*)cbt_all, dim3(gridSz), dim3(256),
                               args, 0, stream);
}

// Round 4
// 257.689 us; speedup vs baseline: 1.6666x; 1.6666x over previous
//
#include <hip/hip_runtime.h>
#include <math.h>

// CBTree contraction, B=4, L=9, d=256.
// g-combine before GEMM (linearity):
//   gL[p]=sum_b lc[b]*h[4p+b], gR[p]=sum_b rc[b]*h[4p+b]
//   h_new[p] = tanh([gL|gR] @ [Wl|Wr].T + vec[p])  (M=n_par, K=512, N=256)
//
// Round 8: 3 launches (was 10). Round 7 proved full-grid cg::grid.sync is
// ~50us/sync (L2 wb/inv + 512 spinners); round 6 showed ~9us/launch-gap.
//   K1 cbt_l7  (576 blk): L7 GEMM loading B direct from fp32 W (no Wfrag
//              dep) + wconv as blocks 512..575.
//   K2 cbt_mfma(128 blk): L6 (unchanged round-6 path); zeroes barrier ctrs.
//   K3 cbt_rest(32 blk):  L5->L4->L3 (split-A MFMA) and L2->L1->L0
//              (n-split fp32-exact VALU, g in LDS), separated by 32-block
//              flag barriers (device-scope acq/rel atomics, guide G16).
// Numerics: identical to round 6 (absmax 0.0117) except L3 now uses bf16 W
// (split-A keeps g exact) -> est absmax ~0.012-0.014, threshold 0.02.

typedef __bf16 bf16x8 __attribute__((ext_vector_type(8)));
typedef __bf16 bf16x4 __attribute__((ext_vector_type(4)));
typedef float f32x4 __attribute__((ext_vector_type(4)));

__device__ __forceinline__ float fast_tanh(float x) {
    float ax = fabsf(x);
    float t = __builtin_amdgcn_exp2f(ax * -2.885390082f);  // 2*log2(e)
    float r = (1.0f - t) * __builtin_amdgcn_rcpf(1.0f + t);
    return copysignf(r, x);
}

// ---------------------------------------------------------------------------
// 32-block flag barrier (device scope). cnt[phase] zeroed by K2 each iter.
// __syncthreads drains each wave's stores (vmcnt) to L2; thread0's release
// fence writes back this XCD's L2; acquire fence after spin invalidates.
// ---------------------------------------------------------------------------
__device__ __forceinline__ void kbar(unsigned* cnt, int phase, unsigned nb) {
    __syncthreads();
    if (threadIdx.x == 0) {
        __threadfence();   // release
        __hip_atomic_fetch_add(&cnt[phase], 1u, __ATOMIC_ACQ_REL,
                               __HIP_MEMORY_SCOPE_AGENT);
        while (__hip_atomic_load(&cnt[phase], __ATOMIC_ACQUIRE,
                                 __HIP_MEMORY_SCOPE_AGENT) < nb)
            __builtin_amdgcn_s_sleep(1);
        __threadfence();   // acquire
    }
    __syncthreads();
}

// ---------------------------------------------------------------------------
// MFMA GEMM tile body, single-pass child reads + split-A (hi+lo bf16).
// Tile 32 x 256 (full N), 256 threads (4 waves, 2x2). Per T-iter (T=0..7):
// read children cols [T*32,T*32+32) ONCE, build {gL_hi,gL_lo,gR_hi,gR_lo}
// in LDS, run K-steps T (gL x B-set T) and T+8 (gR x B-set T+8), each as
// hi-MFMA + lo-MFMA reusing the same B fragments.
// RAWB: load B fragments from fp32 Wl/Wr directly (same RNE bf16 convert
// as wconv -> bit-identical values); else from pre-swizzled Wfrag.
// ---------------------------------------------------------------------------
template <typename CT, typename OT, bool RAWB>
__device__ __forceinline__ void mfma_body(
    const CT* __restrict__ h,          // (4*M, 256) children
    const __bf16* __restrict__ Wfrag,  // swizzled weights (if !RAWB)
    const float* __restrict__ Wl, const float* __restrict__ Wr,
    const float* __restrict__ vec,     // (M, 256)
    OT* __restrict__ out,              // (M, 256)
    int mBase, __bf16* Alds)
{
    const int tid = threadIdx.x;
    const int lane = tid & 63;
    const int w = tid >> 6;
    const int wr = w >> 1, wc = w & 1;   // wave tile: rows wr*16, cols wc*128

    f32x4 acc[8] = {};

    // A staging: 8 threads per parent row, 4 cols each
    const int sm  = tid >> 3;            // parent row 0..31
    const int skq = (tid & 7) * 4;       // col offset 0..28
    const CT* hb = h + (size_t)(mBase + sm) * 1024 + skq;

    float c0[4], c1[4], c2[4], c3[4];
    auto load_h = [&](int k0) {
        if constexpr (sizeof(CT) == 4) {      // fp32 children
            const float4 a = *reinterpret_cast<const float4*>(hb + k0);
            const float4 b = *reinterpret_cast<const float4*>(hb + k0 + 256);
            const float4 c = *reinterpret_cast<const float4*>(hb + k0 + 512);
            const float4 d = *reinterpret_cast<const float4*>(hb + k0 + 768);
            c0[0] = a.x; c0[1] = a.y; c0[2] = a.z; c0[3] = a.w;
            c1[0] = b.x; c1[1] = b.y; c1[2] = b.z; c1[3] = b.w;
            c2[0] = c.x; c2[1] = c.y; c2[2] = c.z; c2[3] = c.w;
            c3[0] = d.x; c3[1] = d.y; c3[2] = d.z; c3[3] = d.w;
        } else {                              // bf16 children
            const bf16x4 a = *reinterpret_cast<const bf16x4*>(hb + k0);
            const bf16x4 b = *reinterpret_cast<const bf16x4*>(hb + k0 + 256);
            const bf16x4 c = *reinterpret_cast<const bf16x4*>(hb + k0 + 512);
            const bf16x4 d = *reinterpret_cast<const bf16x4*>(hb + k0 + 768);
#pragma unroll
            for (int j = 0; j < 4; ++j) {
                c0[j] = (float)a[j]; c1[j] = (float)b[j];
                c2[j] = (float)c[j]; c3[j] = (float)d[j];
            }
        }
    };

    auto store_A = [&]() {
        constexpr float C23 = 2.0f / 3.0f, C13 = 1.0f / 3.0f;
        bf16x4 glh, gll, grh, grl;
#pragma unroll
        for (int j = 0; j < 4; ++j) {
            const float gl = c0[j] + C23 * c1[j] + C13 * c2[j];
            const float gr = C13 * c1[j] + C23 * c2[j] + c3[j];
            glh[j] = (__bf16)gl;
            gll[j] = (__bf16)(gl - (float)glh[j]);
            grh[j] = (__bf16)gr;
            grl[j] = (__bf16)(gr - (float)grh[j]);
        }
        const int o = sm * 40 + skq;
        *reinterpret_cast<bf16x4*>(&Alds[o])        = glh;
        *reinterpret_cast<bf16x4*>(&Alds[o + 1280]) = gll;
        *reinterpret_cast<bf16x4*>(&Alds[o + 2560]) = grh;
        *reinterpret_cast<bf16x4*>(&Alds[o + 3840]) = grl;
    };

    // B fragments: buf0 = gL sets (K-steps 0..7), buf1 = gR sets (8..15),
    // each prefetched one full iteration ahead.
    bf16x8 bfr[2][8];
    auto load_B = [&](int s, int buf) {
        if constexpr (RAWB) {
            // fragment (J=wc*8+j, set s): lane holds Wcat[n][kk..kk+8)
            const int n0 = (wc * 8) * 16 + (lane & 15);
            const int kk = (s & 7) * 32 + (lane >> 4) * 8;
            const float* base = (s < 8) ? (Wl + (size_t)n0 * 256 + kk)
                                        : (Wr + (size_t)n0 * 256 + kk);
#pragma unroll
            for (int j = 0; j < 8; ++j) {
                const float* pp = base + (size_t)j * 4096;   // +16 rows
                const float4 f0 = *reinterpret_cast<const float4*>(pp);
                const float4 f1 = *reinterpret_cast<const float4*>(pp + 4);
                bf16x8 o;
                o[0] = (__bf16)f0.x; o[1] = (__bf16)f0.y;
                o[2] = (__bf16)f0.z; o[3] = (__bf16)f0.w;
                o[4] = (__bf16)f1.x; o[5] = (__bf16)f1.y;
                o[6] = (__bf16)f1.z; o[7] = (__bf16)f1.w;
                bfr[buf][j] = o;
            }
        } else {
            const __bf16* pq =
                Wfrag + ((size_t)wc * 8192 + (size_t)s * 64 + lane) * 8;
#pragma unroll
            for (int j = 0; j < 8; ++j)
                bfr[buf][j] = *reinterpret_cast<const bf16x8*>(pq + (size_t)j * 8192);
        }
    };

    load_h(0);
    load_B(0, 0);
    load_B(8, 1);

    const int arow = (wr * 16 + (lane & 15)) * 40 + (lane >> 4) * 8;

    for (int T = 0; T < 8; ++T) {
        __syncthreads();              // all waves done with previous A tile
        store_A();
        __syncthreads();

        if (T < 7) load_h((T + 1) * 32);   // prefetch next child chunk

        const bf16x8 afLh = *reinterpret_cast<const bf16x8*>(&Alds[arow]);
        const bf16x8 afLl = *reinterpret_cast<const bf16x8*>(&Alds[arow + 1280]);
#pragma unroll
        for (int j = 0; j < 8; ++j)
            acc[j] = __builtin_amdgcn_mfma_f32_16x16x32_bf16(
                afLh, bfr[0][j], acc[j], 0, 0, 0);
#pragma unroll
        for (int j = 0; j < 8; ++j)
            acc[j] = __builtin_amdgcn_mfma_f32_16x16x32_bf16(
                afLl, bfr[0][j], acc[j], 0, 0, 0);

        if (T < 7) load_B(T + 1, 0);       // next gL B-set

        const bf16x8 afRh = *reinterpret_cast<const bf16x8*>(&Alds[arow + 2560]);
        const bf16x8 afRl = *reinterpret_cast<const bf16x8*>(&Alds[arow + 3840]);
#pragma unroll
        for (int j = 0; j < 8; ++j)
            acc[j] = __builtin_amdgcn_mfma_f32_16x16x32_bf16(
                afRh, bfr[1][j], acc[j], 0, 0, 0);
#pragma unroll
        for (int j = 0; j < 8; ++j)
            acc[j] = __builtin_amdgcn_mfma_f32_16x16x32_bf16(
                afRl, bfr[1][j], acc[j], 0, 0, 0);

        if (T < 7) load_B(T + 9, 1);       // next gR B-set
    }

    // epilogue: C/D layout col=lane&15, row=(lane>>4)*4+reg
    const int q = lane >> 4, n16 = lane & 15;
    const int mrow = mBase + wr * 16 + q * 4;
#pragma unroll
    for (int j = 0; j < 8; ++j) {
        const int n = wc * 128 + j * 16 + n16;
#pragma unroll
        for (int r = 0; r < 4; ++r) {
            const size_t idx = (size_t)(mrow + r) * 256 + n;
            out[idx] = (OT)fast_tanh(acc[j][r] + vec[idx]);
        }
    }
}

// ---------------------------------------------------------------------------
// K1: L7 GEMM (blocks 0..511, RAWB) + W swizzle (blocks 512..575).
// Wfrag layout: frag (J,T): lane L holds Wcat[n][k..k+8), n=J*16+(L&15),
// k=T*32+(L>>4)*8.  Flat: Wfrag[(((J*16)+T)*64 + L)*8 + j]
// ---------------------------------------------------------------------------
__global__ __launch_bounds__(256, 2) void cbt_l7(
    const float* __restrict__ vectors, const float* __restrict__ Wl,
    const float* __restrict__ Wr, __bf16* __restrict__ buf7,
    __bf16* __restrict__ Wfrag)
{
    __shared__ __align__(16) __bf16 Alds[4 * 32 * 40];
    if (blockIdx.x >= 512) {    // wconv part: 64 blocks x 256 = 16384 frags*
        const int t = ((int)blockIdx.x - 512) * 256 + (int)threadIdx.x;
        const int L = t & 63;
        const int TJ = t >> 6;
        const int T = TJ & 15;
        const int J = TJ >> 4;
        const int n = J * 16 + (L & 15);
        const int k = T * 32 + (L >> 4) * 8;
        const float* src = (k < 256) ? (Wl + (size_t)n * 256 + k)
                                     : (Wr + (size_t)n * 256 + (k - 256));
        const float4 f0 = *reinterpret_cast<const float4*>(src);
        const float4 f1 = *reinterpret_cast<const float4*>(src + 4);
        bf16x8 o;
        o[0] = (__bf16)f0.x; o[1] = (__bf16)f0.y; o[2] = (__bf16)f0.z; o[3] = (__bf16)f0.w;
        o[4] = (__bf16)f1.x; o[5] = (__bf16)f1.y; o[6] = (__bf16)f1.z; o[7] = (__bf16)f1.w;
        *reinterpret_cast<bf16x8*>(Wfrag + (size_t)t * 8) = o;
        return;
    }
    // L7: fp32 leaves (rows 21845..), vec at rows 5461.., bf16 out
    mfma_body<float, __bf16, true>(vectors + (size_t)21845 * 256, nullptr,
                                   Wl, Wr, vectors + (size_t)5461 * 256,
                                   buf7, (int)blockIdx.x * 32, Alds);
}

// ---------------------------------------------------------------------------
// K2: L6 (bf16 children -> fp32 out), 128 blocks. Also zeroes K3's barrier
// counters (kernel boundary guarantees visibility to K3).
// ---------------------------------------------------------------------------
__global__ __launch_bounds__(256, 2) void cbt_l6(
    const __bf16* __restrict__ h, const __bf16* __restrict__ Wfrag,
    const float* __restrict__ vec, float* __restrict__ out,
    unsigned* __restrict__ bar)
{
    if (blockIdx.x == 0 && threadIdx.x < 8) bar[threadIdx.x] = 0;
    __shared__ __align__(16) __bf16 Alds[4 * 32 * 40];
    mfma_body<__bf16, float, false>(h, Wfrag, nullptr, nullptr, vec, out,
                                    (int)blockIdx.x * 32, Alds);
}

// ---------------------------------------------------------------------------
// VALU level (exact fp32, fp32 W): block b owns n-columns [b*8, b*8+8).
// g-combine computed once into LDS (G[m][k], stride 516 to spread banks),
// then 16-lane-group dot products over K=512.
// ---------------------------------------------------------------------------
__device__ __forceinline__ void valu_level(
    const float* __restrict__ h, const float* __restrict__ Wl,
    const float* __restrict__ Wr, const float* __restrict__ vec,
    float* __restrict__ out, int M, int b, float* G)
{
    const int tid = threadIdx.x;
    constexpr float C23 = 2.0f / 3.0f, C13 = 1.0f / 3.0f;
    constexpr int GS = 516;   // row stride (floats), pads banks

    // G build: e = m*512 + k over M*512 elems
    const int nelem = M * 512;
    for (int e = tid; e < nelem; e += 256) {
        const int m = e >> 9, k = e & 511;
        const float* hm = h + (size_t)m * 1024;
        float g;
        if (k < 256)
            g = hm[k] + C23 * hm[256 + k] + C13 * hm[512 + k];
        else {
            const int kk = k - 256;
            g = C13 * hm[256 + kk] + C23 * hm[512 + kk] + hm[768 + kk];
        }
        G[m * GS + k] = g;
    }
    __syncthreads();

    // dots: 16-lane group per output, outputs o in [0, M*8)
    const int g16 = tid >> 4, l16 = tid & 15;
    const int nout = M * 8;
    for (int o = g16; o < nout; o += 16) {
        const int m = o >> 3;
        const int n = b * 8 + (o & 7);
        const float* wlp = Wl + (size_t)n * 256;
        const float* wrp = Wr + (size_t)n * 256;
        float acc = 0.0f;
#pragma unroll
        for (int q = 0; q < 8; ++q) {
            const int k = l16 * 4 + q * 64;          // 0..508
            const float4 gv = *reinterpret_cast<const float4*>(&G[m * GS + k]);
            const float4 wv = (q < 4)
                ? *reinterpret_cast<const float4*>(wlp + k)
                : *reinterpret_cast<const float4*>(wrp + (k - 256));
            acc += gv.x * wv.x + gv.y * wv.y + gv.z * wv.z + gv.w * wv.w;
        }
#pragma unroll
        for (int off = 8; off >= 1; off >>= 1)
            acc += __shfl_xor(acc, off, 64);
        if (l16 == 0) {
            const size_t idx = (size_t)m * 256 + n;
            out[idx] = fast_tanh(acc + vec[idx]);
        }
    }
    __syncthreads();   // all groups done with G before next level rebuilds
}

// ---------------------------------------------------------------------------
// K3: L5..L0 in one 32-block kernel with flag barriers between levels.
// L5: 32 MFMA tiles (1/block); L4: 8 tiles (blocks 0..7); L3: 2 tiles
// (blocks 0,1); L2/L1/L0: n-split VALU (all 32 blocks, 8 cols each).
// ---------------------------------------------------------------------------
__global__ __launch_bounds__(256) void cbt_rest(
    const float* __restrict__ buf6, const __bf16* __restrict__ Wfrag,
    const float* __restrict__ Wl, const float* __restrict__ Wr,
    const float* __restrict__ vectors,
    float* __restrict__ buf5, float* __restrict__ buf4,
    float* __restrict__ buf3, float* __restrict__ buf2,
    float* __restrict__ buf1, float* __restrict__ outF,
    unsigned* __restrict__ bar)
{
    __shared__ __align__(16) float shG[16 * 516];   // 33KB; also aliases Alds
    __bf16* Alds = (__bf16*)shG;
    const int b = (int)blockIdx.x;
    const unsigned NB = 32;

    // L5: M=1024, fp32->fp32
    mfma_body<float, float, false>(buf6, Wfrag, nullptr, nullptr,
                                   vectors + (size_t)341 * 256, buf5,
                                   b * 32, Alds);
    kbar(bar, 0, NB);
    // L4: M=256
    if (b < 8)
        mfma_body<float, float, false>(buf5, Wfrag, nullptr, nullptr,
                                       vectors + (size_t)85 * 256, buf4,
                                       b * 32, Alds);
    kbar(bar, 1, NB);
    // L3: M=64 (bf16 W via Wfrag; split-A keeps g exact)
    if (b < 2)
        mfma_body<float, float, false>(buf4, Wfrag, nullptr, nullptr,
                                       vectors + (size_t)21 * 256, buf3,
                                       b * 32, Alds);
    kbar(bar, 2, NB);
    // L2..L0: exact fp32 VALU, n-split
    valu_level(buf3, Wl, Wr, vectors + (size_t)5 * 256, buf2, 16, b, shG);
    kbar(bar, 3, NB);
    valu_level(buf2, Wl, Wr, vectors + (size_t)1 * 256, buf1, 4, b, shG);
    kbar(bar, 4, NB);
    valu_level(buf1, Wl, Wr, vectors, outF, 1, b, shG);
}

// ---------------------------------------------------------------------------
extern "C" void kernel_launch(void* const* d_in, const int* in_sizes, int n_in,
                              void* d_out, int out_size, void* d_ws, size_t ws_size,
                              hipStream_t stream) {
    const float* vectors = (const float*)d_in[0];
    const float* Wl = (const float*)d_in[1];
    const float* Wr = (const float*)d_in[2];
    float* outF = (float*)d_out;

    // ws layout:
    //   buf7  bf16  16384x256 (8 MB)   L7 out
    //   buf6  f32    4096x256 (4 MB)   L6 out
    //   buf5  f32    1024x256 (1 MB)   L5 out
    //   buf4  f32     256x256 (256 KB) L4 out
    //   buf3  f32      64x256 (64 KB)  L3 out
    //   buf2  f32      16x256 (16 KB)  L2 out
    //   buf1  f32       4x256 (4 KB)   L1 out
    //   Wfrag bf16  16384x8   (256 KB)
    //   bar   u32   x8        (32 B)   K3 flag-barrier counters
    char* p = (char*)d_ws;
    __bf16* buf7 = (__bf16*)p;           p += (size_t)16384 * 256 * 2;
    float*  buf6 = (float*)p;            p += (size_t)4096 * 256 * 4;
    float*  buf5 = (float*)p;            p += (size_t)1024 * 256 * 4;
    float*  buf4 = (float*)p;            p += (size_t)256 * 256 * 4;
    float*  buf3 = (float*)p;            p += (size_t)64 * 256 * 4;
    float*  buf2 = (float*)p;            p += (size_t)16 * 256 * 4;
    float*  buf1 = (float*)p;            p += (size_t)4 * 256 * 4;
    __bf16* Wfrag = (__bf16*)p;          p += (size_t)16384 * 8 * 2;
    unsigned* bar = (unsigned*)p;

    // K1: L7 (512 tile-blocks) + wconv (64 blocks)
    hipLaunchKernelGGL(cbt_l7, dim3(576), dim3(256), 0, stream,
                       vectors, Wl, Wr, buf7, Wfrag);
    // K2: L6 (also zeroes K3 barrier counters)
    hipLaunchKernelGGL(cbt_l6, dim3(128), dim3(256), 0, stream,
                       buf7, Wfrag, vectors + (size_t)1365 * 256, buf6, bar);
    // K3: L5..L0 with internal flag barriers
    hipLaunchKernelGGL(cbt_rest, dim3(32), dim3(256), 0, stream,
                       buf6, Wfrag, Wl, Wr, vectors,
                       buf5, buf4, buf3, buf2, buf1, outF, bar);
}

// Round 5
// 226.587 us; speedup vs baseline: 1.8953x; 1.1373x over previous
//
#include <hip/hip_runtime.h>
#include <math.h>

// CBTree contraction, B=4, L=9, d=256.
// g-combine before GEMM (linearity):
//   gL[p]=sum_b lc[b]*h[4p+b], gR[p]=sum_b rc[b]*h[4p+b]
//   h_new[p] = tanh([gL|gR] @ [Wl|Wr].T + vec[p])  (M=n_par, K=512, N=256)
//
// Round 9: revert round-8's RAWB B-loads (uncoalesced 1KB-stride scatter ->
// l7 77us @ 4% MfmaUtil). B comes from pre-swizzled Wfrag again (coalesced,
// L1/L2-hot register loads); wconv is its own 64-block launch. NEW: A-tile
// LDS is double-buffered (8 regions, 20KB) -> ONE __syncthreads per K-iter
// (was 2): store tile T+1 into buf q while MFMAing tile T from buf p.
// Numerics identical to round 8 (absmax 0.0088): split-A hi/lo, fp32
// intermediates L6..L1, L3 on bf16 Wfrag, exact fp32 tail. cbt_rest
// unchanged (isolates tail cost for next round's read).
// Launches: wconv, l7 (512 blk), l6 (128 blk), rest (32 blk + kbar).

typedef __bf16 bf16x8 __attribute__((ext_vector_type(8)));
typedef __bf16 bf16x4 __attribute__((ext_vector_type(4)));
typedef float f32x4 __attribute__((ext_vector_type(4)));

__device__ __forceinline__ float fast_tanh(float x) {
    float ax = fabsf(x);
    float t = __builtin_amdgcn_exp2f(ax * -2.885390082f);  // 2*log2(e)
    float r = (1.0f - t) * __builtin_amdgcn_rcpf(1.0f + t);
    return copysignf(r, x);
}

// ---------------------------------------------------------------------------
// 32-block flag barrier (device scope). cnt[phase] zeroed by cbt_l6.
// ---------------------------------------------------------------------------
__device__ __forceinline__ void kbar(unsigned* cnt, int phase, unsigned nb) {
    __syncthreads();
    if (threadIdx.x == 0) {
        __threadfence();   // release
        __hip_atomic_fetch_add(&cnt[phase], 1u, __ATOMIC_ACQ_REL,
                               __HIP_MEMORY_SCOPE_AGENT);
        while (__hip_atomic_load(&cnt[phase], __ATOMIC_ACQUIRE,
                                 __HIP_MEMORY_SCOPE_AGENT) < nb)
            __builtin_amdgcn_s_sleep(1);
        __threadfence();   // acquire
    }
    __syncthreads();
}

// ---------------------------------------------------------------------------
// W swizzle: Wfrag holds [Wl|Wr] (N=256 x K=512) in MFMA B-fragment order.
// Fragment (J,T): 64 lanes x 8 bf16; lane L holds B[k=T*32+(L>>4)*8+j][n=J*16+(L&15)]
//   = Wcat[n][k].  Flat: Wfrag[(((J*16)+T)*64 + L)*8 + j]
// ---------------------------------------------------------------------------
__global__ __launch_bounds__(256) void cbt_wconv(
    const float* __restrict__ Wl, const float* __restrict__ Wr,
    __bf16* __restrict__ Wfrag)
{
    const int t = blockIdx.x * 256 + threadIdx.x;   // 0..16383
    const int L = t & 63;
    const int TJ = t >> 6;
    const int T = TJ & 15;
    const int J = TJ >> 4;
    const int n = J * 16 + (L & 15);
    const int k = T * 32 + (L >> 4) * 8;
    const float* src = (k < 256) ? (Wl + (size_t)n * 256 + k)
                                 : (Wr + (size_t)n * 256 + (k - 256));
    const float4 f0 = *reinterpret_cast<const float4*>(src);
    const float4 f1 = *reinterpret_cast<const float4*>(src + 4);
    bf16x8 o;
    o[0] = (__bf16)f0.x; o[1] = (__bf16)f0.y; o[2] = (__bf16)f0.z; o[3] = (__bf16)f0.w;
    o[4] = (__bf16)f1.x; o[5] = (__bf16)f1.y; o[6] = (__bf16)f1.z; o[7] = (__bf16)f1.w;
    *reinterpret_cast<bf16x8*>(Wfrag + (size_t)t * 8) = o;
}

// ---------------------------------------------------------------------------
// MFMA GEMM tile body. Tile 32 x 256 (full N), 256 threads (4 waves, 2x2).
// Single-pass child reads + split-A (hi+lo bf16) + DOUBLE-BUFFERED A LDS:
// per T-iter (one barrier): MFMA tile T from buf p while storing tile T+1
// into buf q and prefetching tile T+2 child regs + next B-sets.
// Alds: 8 regions x 1280 elems (32 rows x stride 40): buf*4 + {Lh,Ll,Rh,Rl}.
// ---------------------------------------------------------------------------
template <typename CT, typename OT>
__device__ __forceinline__ void mfma_body(
    const CT* __restrict__ h,          // (4*M, 256) children
    const __bf16* __restrict__ Wfrag,  // swizzled weights
    const float* __restrict__ vec,     // (M, 256)
    OT* __restrict__ out,              // (M, 256)
    int mBase, __bf16* Alds)
{
    const int tid = threadIdx.x;
    const int lane = tid & 63;
    const int w = tid >> 6;
    const int wr = w >> 1, wc = w & 1;   // wave tile: rows wr*16, cols wc*128

    f32x4 acc[8] = {};

    // A staging: 8 threads per parent row, 4 cols each
    const int sm  = tid >> 3;            // parent row 0..31
    const int skq = (tid & 7) * 4;       // col offset 0..28
    const CT* hb = h + (size_t)(mBase + sm) * 1024 + skq;

    float c0[4], c1[4], c2[4], c3[4];
    auto load_h = [&](int k0) {
        if constexpr (sizeof(CT) == 4) {      // fp32 children
            const float4 a = *reinterpret_cast<const float4*>(hb + k0);
            const float4 b = *reinterpret_cast<const float4*>(hb + k0 + 256);
            const float4 c = *reinterpret_cast<const float4*>(hb + k0 + 512);
            const float4 d = *reinterpret_cast<const float4*>(hb + k0 + 768);
            c0[0] = a.x; c0[1] = a.y; c0[2] = a.z; c0[3] = a.w;
            c1[0] = b.x; c1[1] = b.y; c1[2] = b.z; c1[3] = b.w;
            c2[0] = c.x; c2[1] = c.y; c2[2] = c.z; c2[3] = c.w;
            c3[0] = d.x; c3[1] = d.y; c3[2] = d.z; c3[3] = d.w;
        } else {                              // bf16 children
            const bf16x4 a = *reinterpret_cast<const bf16x4*>(hb + k0);
            const bf16x4 b = *reinterpret_cast<const bf16x4*>(hb + k0 + 256);
            const bf16x4 c = *reinterpret_cast<const bf16x4*>(hb + k0 + 512);
            const bf16x4 d = *reinterpret_cast<const bf16x4*>(hb + k0 + 768);
#pragma unroll
            for (int j = 0; j < 4; ++j) {
                c0[j] = (float)a[j]; c1[j] = (float)b[j];
                c2[j] = (float)c[j]; c3[j] = (float)d[j];
            }
        }
    };

    auto store_A = [&](int buf) {
        constexpr float C23 = 2.0f / 3.0f, C13 = 1.0f / 3.0f;
        bf16x4 glh, gll, grh, grl;
#pragma unroll
        for (int j = 0; j < 4; ++j) {
            const float gl = c0[j] + C23 * c1[j] + C13 * c2[j];
            const float gr = C13 * c1[j] + C23 * c2[j] + c3[j];
            glh[j] = (__bf16)gl;
            gll[j] = (__bf16)(gl - (float)glh[j]);
            grh[j] = (__bf16)gr;
            grl[j] = (__bf16)(gr - (float)grh[j]);
        }
        const int o = buf * 5120 + sm * 40 + skq;
        *reinterpret_cast<bf16x4*>(&Alds[o])        = glh;
        *reinterpret_cast<bf16x4*>(&Alds[o + 1280]) = gll;
        *reinterpret_cast<bf16x4*>(&Alds[o + 2560]) = grh;
        *reinterpret_cast<bf16x4*>(&Alds[o + 3840]) = grl;
    };

    // B fragments: buf0 = current gL set, buf1 = current gR set; each slot
    // refilled with the next set right after its MFMAs (L1/L2-hot Wfrag).
    bf16x8 bfr[2][8];
    const __bf16* Wb = Wfrag + ((size_t)wc * 8192 + lane) * 8;  // J0=wc*8
    auto load_B = [&](int s, int buf) {
        const __bf16* p = Wb + (size_t)s * 512;
#pragma unroll
        for (int j = 0; j < 8; ++j)
            bfr[buf][j] = *reinterpret_cast<const bf16x8*>(p + (size_t)j * 8192);
    };

    // prologue: tile0 -> buf0; tile1 regs; first B sets
    load_h(0);
    load_B(0, 0);
    load_B(8, 1);
    store_A(0);
    load_h(32);
    __syncthreads();

    const int arow = (wr * 16 + (lane & 15)) * 40 + (lane >> 4) * 8;

    for (int T = 0; T < 8; ++T) {
        const int p = (T & 1) * 5120;
        const int q = ((T + 1) & 1);

        if (T < 7) store_A(q);             // tile T+1 -> other buffer
        if (T < 6) load_h((T + 2) * 32);   // tile T+2 -> regs

        const bf16x8 afLh = *reinterpret_cast<const bf16x8*>(&Alds[p + arow]);
        const bf16x8 afLl = *reinterpret_cast<const bf16x8*>(&Alds[p + arow + 1280]);
#pragma unroll
        for (int j = 0; j < 8; ++j)
            acc[j] = __builtin_amdgcn_mfma_f32_16x16x32_bf16(
                afLh, bfr[0][j], acc[j], 0, 0, 0);
#pragma unroll
        for (int j = 0; j < 8; ++j)
            acc[j] = __builtin_amdgcn_mfma_f32_16x16x32_bf16(
                afLl, bfr[0][j], acc[j], 0, 0, 0);

        if (T < 7) load_B(T + 1, 0);       // next gL B-set

        const bf16x8 afRh = *reinterpret_cast<const bf16x8*>(&Alds[p + arow + 2560]);
        const bf16x8 afRl = *reinterpret_cast<const bf16x8*>(&Alds[p + arow + 3840]);
#pragma unroll
        for (int j = 0; j < 8; ++j)
            acc[j] = __builtin_amdgcn_mfma_f32_16x16x32_bf16(
                afRh, bfr[1][j], acc[j], 0, 0, 0);
#pragma unroll
        for (int j = 0; j < 8; ++j)
            acc[j] = __builtin_amdgcn_mfma_f32_16x16x32_bf16(
                afRl, bfr[1][j], acc[j], 0, 0, 0);

        if (T < 7) load_B(T + 9, 1);       // next gR B-set

        if (T < 7) __syncthreads();        // tile T+1 now visible; reads of p done
    }

    // epilogue: C/D layout col=lane&15, row=(lane>>4)*4+reg
    const int q16 = lane >> 4, n16 = lane & 15;
    const int mrow = mBase + wr * 16 + q16 * 4;
#pragma unroll
    for (int j = 0; j < 8; ++j) {
        const int n = wc * 128 + j * 16 + n16;
#pragma unroll
        for (int r = 0; r < 4; ++r) {
            const size_t idx = (size_t)(mrow + r) * 256 + n;
            out[idx] = (OT)fast_tanh(acc[j][r] + vec[idx]);
        }
    }
}

// ---------------------------------------------------------------------------
// K1: L7 (fp32 leaves -> bf16 out), 512 blocks.
// ---------------------------------------------------------------------------
__global__ __launch_bounds__(256, 2) void cbt_l7(
    const float* __restrict__ vectors, const __bf16* __restrict__ Wfrag,
    __bf16* __restrict__ buf7)
{
    __shared__ __align__(16) __bf16 Alds[8 * 32 * 40];
    mfma_body<float, __bf16>(vectors + (size_t)21845 * 256, Wfrag,
                             vectors + (size_t)5461 * 256, buf7,
                             (int)blockIdx.x * 32, Alds);
}

// ---------------------------------------------------------------------------
// K2: L6 (bf16 children -> fp32 out), 128 blocks. Zeroes K3's barrier ctrs.
// ---------------------------------------------------------------------------
__global__ __launch_bounds__(256, 2) void cbt_l6(
    const __bf16* __restrict__ h, const __bf16* __restrict__ Wfrag,
    const float* __restrict__ vec, float* __restrict__ out,
    unsigned* __restrict__ bar)
{
    if (blockIdx.x == 0 && threadIdx.x < 8) bar[threadIdx.x] = 0;
    __shared__ __align__(16) __bf16 Alds[8 * 32 * 40];
    mfma_body<__bf16, float>(h, Wfrag, vec, out, (int)blockIdx.x * 32, Alds);
}

// ---------------------------------------------------------------------------
// VALU level (exact fp32, fp32 W): block b owns n-columns [b*8, b*8+8).
// g-combine computed once into LDS (G[m][k], stride 516), then 16-lane-group
// dot products over K=512.
// ---------------------------------------------------------------------------
__device__ __forceinline__ void valu_level(
    const float* __restrict__ h, const float* __restrict__ Wl,
    const float* __restrict__ Wr, const float* __restrict__ vec,
    float* __restrict__ out, int M, int b, float* G)
{
    const int tid = threadIdx.x;
    constexpr float C23 = 2.0f / 3.0f, C13 = 1.0f / 3.0f;
    constexpr int GS = 516;

    const int nelem = M * 512;
    for (int e = tid; e < nelem; e += 256) {
        const int m = e >> 9, k = e & 511;
        const float* hm = h + (size_t)m * 1024;
        float g;
        if (k < 256)
            g = hm[k] + C23 * hm[256 + k] + C13 * hm[512 + k];
        else {
            const int kk = k - 256;
            g = C13 * hm[256 + kk] + C23 * hm[512 + kk] + hm[768 + kk];
        }
        G[m * GS + k] = g;
    }
    __syncthreads();

    const int g16 = tid >> 4, l16 = tid & 15;
    const int nout = M * 8;
    for (int o = g16; o < nout; o += 16) {
        const int m = o >> 3;
        const int n = b * 8 + (o & 7);
        const float* wlp = Wl + (size_t)n * 256;
        const float* wrp = Wr + (size_t)n * 256;
        float acc = 0.0f;
#pragma unroll
        for (int q = 0; q < 8; ++q) {
            const int k = l16 * 4 + q * 64;
            const float4 gv = *reinterpret_cast<const float4*>(&G[m * GS + k]);
            const float4 wv = (q < 4)
                ? *reinterpret_cast<const float4*>(wlp + k)
                : *reinterpret_cast<const float4*>(wrp + (k - 256));
            acc += gv.x * wv.x + gv.y * wv.y + gv.z * wv.z + gv.w * wv.w;
        }
#pragma unroll
        for (int off = 8; off >= 1; off >>= 1)
            acc += __shfl_xor(acc, off, 64);
        if (l16 == 0) {
            const size_t idx = (size_t)m * 256 + n;
            out[idx] = fast_tanh(acc + vec[idx]);
        }
    }
    __syncthreads();
}

// ---------------------------------------------------------------------------
// K3: L5..L0 in one 32-block kernel with flag barriers between levels.
// ---------------------------------------------------------------------------
__global__ __launch_bounds__(256) void cbt_rest(
    const float* __restrict__ buf6, const __bf16* __restrict__ Wfrag,
    const float* __restrict__ Wl, const float* __restrict__ Wr,
    const float* __restrict__ vectors,
    float* __restrict__ buf5, float* __restrict__ buf4,
    float* __restrict__ buf3, float* __restrict__ buf2,
    float* __restrict__ buf1, float* __restrict__ outF,
    unsigned* __restrict__ bar)
{
    __shared__ __align__(16) float shG[16 * 516];   // 33KB; aliases Alds (20KB)
    __bf16* Alds = (__bf16*)shG;
    const int b = (int)blockIdx.x;
    const unsigned NB = 32;

    // L5: M=1024, fp32->fp32
    mfma_body<float, float>(buf6, Wfrag, vectors + (size_t)341 * 256, buf5,
                            b * 32, Alds);
    kbar(bar, 0, NB);
    // L4: M=256
    if (b < 8)
        mfma_body<float, float>(buf5, Wfrag, vectors + (size_t)85 * 256, buf4,
                                b * 32, Alds);
    kbar(bar, 1, NB);
    // L3: M=64 (bf16 W via Wfrag; split-A keeps g exact)
    if (b < 2)
        mfma_body<float, float>(buf4, Wfrag, vectors + (size_t)21 * 256, buf3,
                                b * 32, Alds);
    kbar(bar, 2, NB);
    // L2..L0: exact fp32 VALU, n-split
    valu_level(buf3, Wl, Wr, vectors + (size_t)5 * 256, buf2, 16, b, shG);
    kbar(bar, 3, NB);
    valu_level(buf2, Wl, Wr, vectors + (size_t)1 * 256, buf1, 4, b, shG);
    kbar(bar, 4, NB);
    valu_level(buf1, Wl, Wr, vectors, outF, 1, b, shG);
}

// ---------------------------------------------------------------------------
extern "C" void kernel_launch(void* const* d_in, const int* in_sizes, int n_in,
                              void* d_out, int out_size, void* d_ws, size_t ws_size,
                              hipStream_t stream) {
    const float* vectors = (const float*)d_in[0];
    const float* Wl = (const float*)d_in[1];
    const float* Wr = (const float*)d_in[2];
    float* outF = (float*)d_out;

    // ws layout:
    //   buf7  bf16  16384x256 (8 MB)   L7 out
    //   buf6  f32    4096x256 (4 MB)   L6 out
    //   buf5  f32    1024x256 (1 MB)   L5 out
    //   buf4  f32     256x256 (256 KB) L4 out
    //   buf3  f32      64x256 (64 KB)  L3 out
    //   buf2  f32      16x256 (16 KB)  L2 out
    //   buf1  f32       4x256 (4 KB)   L1 out
    //   Wfrag bf16  16384x8   (256 KB)
    //   bar   u32   x8        (32 B)
    char* p = (char*)d_ws;
    __bf16* buf7 = (__bf16*)p;           p += (size_t)16384 * 256 * 2;
    float*  buf6 = (float*)p;            p += (size_t)4096 * 256 * 4;
    float*  buf5 = (float*)p;            p += (size_t)1024 * 256 * 4;
    float*  buf4 = (float*)p;            p += (size_t)256 * 256 * 4;
    float*  buf3 = (float*)p;            p += (size_t)64 * 256 * 4;
    float*  buf2 = (float*)p;            p += (size_t)16 * 256 * 4;
    float*  buf1 = (float*)p;            p += (size_t)4 * 256 * 4;
    __bf16* Wfrag = (__bf16*)p;          p += (size_t)16384 * 8 * 2;
    unsigned* bar = (unsigned*)p;

    // K0: weight swizzle
    hipLaunchKernelGGL(cbt_wconv, dim3(64), dim3(256), 0, stream, Wl, Wr, Wfrag);
    // K1: L7 (512 tile-blocks)
    hipLaunchKernelGGL(cbt_l7, dim3(512), dim3(256), 0, stream,
                       vectors, Wfrag, buf7);
    // K2: L6 (also zeroes K3 barrier counters)
    hipLaunchKernelGGL(cbt_l6, dim3(128), dim3(256), 0, stream,
                       buf7, Wfrag, vectors + (size_t)1365 * 256, buf6, bar);
    // K3: L5..L0 with internal flag barriers
    hipLaunchKernelGGL(cbt_rest, dim3(32), dim3(256), 0, stream,
                       buf6, Wfrag, Wl, Wr, vectors,
                       buf5, buf4, buf3, buf2, buf1, outF, bar);
}